// Round 13
// baseline (525.585 us; speedup 1.0000x reference)
//
#include <hip/hip_runtime.h>

// B=2, L=2048, D=1024, H=16, Hd=64, no causal mask. Inputs f32 (device-sniffed).

#define D_MODEL 1024
#define NH 16
#define HD 64
#define BATCH 2
#define SEQ 2048
#define MROWS (BATCH*SEQ)   // 4096

typedef unsigned short u16;
typedef __bf16 bf16x8 __attribute__((ext_vector_type(8)));
typedef float f32x4 __attribute__((ext_vector_type(4)));
typedef float f32x16 __attribute__((ext_vector_type(16)));

__device__ __forceinline__ u16 f2bf(float f){
    __bf16 h = (__bf16)f;                    // hw v_cvt (RNE) on gfx950
    return __builtin_bit_cast(u16, h);
}
__device__ __forceinline__ float fast_exp2(float x){ return __builtin_amdgcn_exp2f(x); }

// async global->LDS, 16B per lane (m97 pattern). LDS dest must be
// wave-uniform base + lane*16 in issue order.
__device__ __forceinline__ void stage16(const void* g, void* l){
#if __has_builtin(__builtin_amdgcn_global_load_lds)
    __builtin_amdgcn_global_load_lds(
        (__attribute__((address_space(1))) void*)(unsigned long long)(g),
        (__attribute__((address_space(3))) void*)(unsigned int)(unsigned long long)(l),
        16, 0, 0);
#else
    *(uint4*)l = *(const uint4*)g;
#endif
}

// f32-vs-bf16 sniff on a pristine input buffer (deterministic, graph-safe).
__device__ __forceinline__ int detect_f32_block(const u16* q, int tid){
    __shared__ int flag;
    if (tid < 64){
        unsigned e = (q[2*tid]>>7)&0xFFu;
        bool hit = (e>=115u)&&(e<=132u);
        unsigned long long m = __ballot(hit);
        if (tid==0) flag = (__popcll(m) < 32) ? 1 : 0;
    }
    __syncthreads();
    return flag;
}

// ---------------------------------------------------------------------------
// One launch converts q,k,v,Wq,Wk,Wv,Wo into contiguous bf16 ws regions.
// ---------------------------------------------------------------------------
__global__ __launch_bounds__(256)
void convert_all(const u16* __restrict__ q, const u16* __restrict__ k,
                 const u16* __restrict__ v, const u16* __restrict__ Wq,
                 const u16* __restrict__ Wk, const u16* __restrict__ Wv,
                 const u16* __restrict__ Wo, u16* __restrict__ dst)
{
    int isf32 = detect_f32_block(q, threadIdx.x);
    int bid = blockIdx.x;
    const u16* src; int lb;
    if      (bid < 4096)  { src=q;  lb=bid; }
    else if (bid < 8192)  { src=k;  lb=bid-4096; }
    else if (bid < 12288) { src=v;  lb=bid-8192; }
    else if (bid < 13312) { src=Wq; lb=bid-12288; }
    else if (bid < 14336) { src=Wk; lb=bid-13312; }
    else if (bid < 15360) { src=Wv; lb=bid-14336; }
    else                  { src=Wo; lb=bid-15360; }
    size_t so = (size_t)lb*1024 + threadIdx.x*4;
    size_t dofs = (size_t)bid*1024 + threadIdx.x*4;
    if (isf32){
        float4 x = *(const float4*)((const float*)src + so);
        ushort4 o; o.x=f2bf(x.x); o.y=f2bf(x.y); o.z=f2bf(x.z); o.w=f2bf(x.w);
        *(ushort4*)(dst+dofs) = o;
    } else {
        *(ushort4*)(dst+dofs) = *(const ushort4*)(src+so);
    }
}

// ---------------------------------------------------------------------------
// Fused Q/K/V projection GEMM, BK=64, symmetric double-buffer, 512 threads /
// 8 waves (R11-verified). Wave tile 32x64 (acc 2x4), staging 2 chunks/thread
// per operand. 64KB LDS, 2 blocks/CU -> 16 waves/CU. XOR-8 pre-swizzled
// source chunks + same XOR at frag read (0 conflicts). XCD-bijective swizzle.
// z<2 -> split-head [B,H,L,HD]; z==2 -> transposed [B,H,HD,L] for PV.
// z==0 folds the softmax scale 1/sqrt(64)*log2(e) into Q.
// ---------------------------------------------------------------------------
__global__ __launch_bounds__(512)
void gemm_qkv(const u16* __restrict__ qb, const u16* __restrict__ kb,
              const u16* __restrict__ vb, const u16* __restrict__ Wqb,
              const u16* __restrict__ Wkb, const u16* __restrict__ Wvb,
              u16* __restrict__ Qh, u16* __restrict__ Kh, u16* __restrict__ Vt)
{
    const int K = 1024;
    __shared__ __align__(16) u16 lA[2][128*64];   // 32KB
    __shared__ __align__(16) u16 lB[2][128*64];   // 32KB

    // bijective XCD remap of (x,y,z): 768 = 8 xcd * (8 x * 12 panels)
    const int lid = blockIdx.x + 8*(blockIdx.y + 32*blockIdx.z);
    const int xcd = lid & 7, loc = lid >> 3;
    const int xb = loc & 7, p = loc >> 3;
    const int yz = xcd*12 + p;
    const int z = yz >> 5, yb = yz & 31;

    const u16* A  = (z==0)? qb  : (z==1)? kb  : vb;
    const u16* Bt = (z==0)? Wqb : (z==1)? Wkb : Wvb;

    const int tid  = threadIdx.x;
    const int wid  = tid>>6, lane = tid&63;
    const int quad = lane>>4, l16 = lane&15;
    const int wm = (wid&3)*32, wn = (wid>>2)*64;   // 8 waves: 4 row x 2 col
    const int row0 = yb*128, col0 = xb*128;

    f32x4 acc[2][4];
    #pragma unroll
    for (int i=0;i<2;i++)
        #pragma unroll
        for (int j=0;j<4;j++) acc[i][j] = (f32x4){0.f,0.f,0.f,0.f};

    // 1024 chunks per operand; 512 threads -> 2 chunks/thread (XOR source)
    #define QKV_STAGE(buf, k0)                                                 \
        _Pragma("unroll")                                                      \
        for (int s=0;s<2;s++){                                                 \
            int c = tid + s*512;                                               \
            int row = c>>3, cr = c&7;                                          \
            int gc = cr ^ (row&7);                                             \
            stage16(&A [(size_t)(row0+row)*K + (k0) + gc*8], &lA[buf][c*8]);   \
            stage16(&Bt[(size_t)(col0+row)*K + (k0) + gc*8], &lB[buf][c*8]);   \
        }

    QKV_STAGE(0, 0)
    __syncthreads();

    int cur = 0;
    for (int t=0; t<16; ++t){
        if (t < 15) QKV_STAGE(cur^1, (t+1)*64)     // async over this tile's compute
        #pragma unroll
        for (int kk=0;kk<2;kk++){
            bf16x8 af[2], bfr[4];
            #pragma unroll
            for (int mi=0;mi<2;mi++){
                int r = wm + mi*16 + l16;
                af[mi] = *(const bf16x8*)&lA[cur][r*64 + ((kk*4+quad) ^ (r&7))*8];
            }
            #pragma unroll
            for (int ni=0;ni<4;ni++){
                int r = wn + ni*16 + l16;
                bfr[ni] = *(const bf16x8*)&lB[cur][r*64 + ((kk*4+quad) ^ (r&7))*8];
            }
            #pragma unroll
            for (int mi=0;mi<2;mi++)
                #pragma unroll
                for (int ni=0;ni<4;ni++)
                    acc[mi][ni] = __builtin_amdgcn_mfma_f32_16x16x32_bf16(af[mi], bfr[ni], acc[mi][ni], 0,0,0);
        }
        __syncthreads();   // single drain: vmcnt(0)+barrier, next buf ready
        cur ^= 1;
    }
    #undef QKV_STAGE

    const float qsc = (z==0) ? 0.18033688011112042f : 1.0f; // 0.125*log2(e)
    u16* Csh = (z==0)? Qh : Kh;
    #pragma unroll
    for (int mi=0;mi<2;mi++){
        #pragma unroll
        for (int ni=0;ni<4;ni++){
            int col = col0 + wn + ni*16 + l16;
            #pragma unroll
            for (int r=0;r<4;r++){
                int row = row0 + wm + mi*16 + quad*4 + r;
                u16 o = f2bf(acc[mi][ni][r]*qsc);
                int b = row>>11, i = row&2047, h = col>>6, d = col&63;
                if (z<2) Csh[((((size_t)(b*NH+h))*SEQ + i)<<6) + d] = o;
                else     Vt[((size_t)((b*NH+h)*HD + d))*SEQ + i] = o;
            }
        }
    }
}

// ---------------------------------------------------------------------------
// Output projection: C = ctx * Wo^T. 64x128 tiles, BK=64, symmetric dbuf,
// 512 threads / 8 waves (R12-verified): wave tile 32x32 (acc 2x2), staging
// A 1 + B 2 chunks per thread. LDS 48KB -> 2 blocks/CU -> 16 waves/CU.
// XOR-8 source+read swizzle. XCD swizzle.
// ---------------------------------------------------------------------------
__global__ __launch_bounds__(512)
void gemm_out(const u16* __restrict__ A, const u16* __restrict__ Bt,
              void* __restrict__ Cv, const u16* __restrict__ qref)
{
    const int K = 1024, N = 1024;
    int outf32 = detect_f32_block(qref, threadIdx.x);
    __shared__ __align__(16) u16 lA[2][64*64];    // 16KB
    __shared__ __align__(16) u16 lB[2][128*64];   // 32KB
    const int tid  = threadIdx.x;
    const int wid  = tid>>6, lane = tid&63;
    const int quad = lane>>4, l16 = lane&15;
    const int wm = (wid&1)*32, wn = (wid>>1)*32;   // 8 waves: 2 row x 4 col

    // bijective XCD remap: 512 = 8 xcd * (8 x * 8 y)
    const int lid = blockIdx.x + 8*blockIdx.y;
    const int xcd = lid & 7, loc = lid >> 3;
    const int xb = loc & 7, yb = xcd*8 + (loc>>3);
    const int row0 = yb*64, col0 = xb*128;

    f32x4 acc[2][2];
    #pragma unroll
    for (int i=0;i<2;i++)
        #pragma unroll
        for (int j=0;j<2;j++) acc[i][j] = (f32x4){0.f,0.f,0.f,0.f};

    // A: 512 chunks -> 1/thread; B: 1024 chunks -> 2/thread (XOR source)
    #define OUT_STAGE(buf, k0)                                                 \
        {                                                                      \
            int c2 = tid;                                                      \
            int row = c2>>3, cr = c2&7;                                        \
            int gc = cr ^ (row&7);                                             \
            stage16(&A[(size_t)(row0+row)*K + (k0) + gc*8], &lA[buf][c2*8]);   \
        }                                                                      \
        _Pragma("unroll")                                                      \
        for (int s=0;s<2;s++){                                                 \
            int c = tid + s*512;                                               \
            int row = c>>3, cr = c&7;                                          \
            int gc = cr ^ (row&7);                                             \
            stage16(&Bt[(size_t)(col0+row)*K + (k0) + gc*8], &lB[buf][c*8]);   \
        }

    OUT_STAGE(0, 0)
    __syncthreads();

    int cur = 0;
    for (int t=0; t<16; ++t){
        if (t < 15) OUT_STAGE(cur^1, (t+1)*64)
        #pragma unroll
        for (int kk=0;kk<2;kk++){
            bf16x8 af[2], bfr[2];
            #pragma unroll
            for (int mi=0;mi<2;mi++){
                int r = wm + mi*16 + l16;
                af[mi] = *(const bf16x8*)&lA[cur][r*64 + ((kk*4+quad) ^ (r&7))*8];
            }
            #pragma unroll
            for (int ni=0;ni<2;ni++){
                int r = wn + ni*16 + l16;
                bfr[ni] = *(const bf16x8*)&lB[cur][r*64 + ((kk*4+quad) ^ (r&7))*8];
            }
            #pragma unroll
            for (int mi=0;mi<2;mi++)
                #pragma unroll
                for (int ni=0;ni<2;ni++)
                    acc[mi][ni] = __builtin_amdgcn_mfma_f32_16x16x32_bf16(af[mi], bfr[ni], acc[mi][ni], 0,0,0);
        }
        __syncthreads();
        cur ^= 1;
    }
    #undef OUT_STAGE

    #pragma unroll
    for (int mi=0;mi<2;mi++){
        #pragma unroll
        for (int ni=0;ni<2;ni++){
            int col = col0 + wn + ni*16 + l16;
            #pragma unroll
            for (int r=0;r<4;r++){
                int row = row0 + wm + mi*16 + quad*4 + r;
                float f = acc[mi][ni][r];
                if (outf32) ((float*)Cv)[(size_t)row*N + col] = f;
                else        ((u16*)Cv)[(size_t)row*N + col] = f2bf(f);
            }
        }
    }
}

// ---------------------------------------------------------------------------
// Flash attention v7: v6's verified compute core, K/V SINGLE-buffered in LDS
// (the VGPR prefetch already provides the double-buffering): LDS 67.6->33.8KB
// -> 4 blocks/CU -> 32 waves/CU (was 2 blocks / 16 waves, occupancy 34%).
// Cost: one extra barrier per tile (commit-after-reads) draining register-
// resident data only. Merge staged in 2 rounds (33.8KB exact / 17KB) with odd
// float strides (33/17) to stay conflict-free in the smaller footprint.
// ---------------------------------------------------------------------------
#define KVT 4096                      // K buffer: 64 rows * 64 elems
#define VROW 68                       // V row pitch (pad 4)
#define VVT (64*VROW)                 // 4352 elems per V buffer
// elem offset of 16B chunk c8 (0..7) in swizzled K row (stride 64):
#define SW(row, c8) ((row)*64 + ((((c8) ^ ((row)&7)))*8))

__global__ __launch_bounds__(512, 8)
void attn3(const u16* __restrict__ Qh, const u16* __restrict__ Kh,
           const u16* __restrict__ Vt, const int* __restrict__ mask,
           u16* __restrict__ ctx)
{
    // single-buffered: [hf] K then [hf] V; merge overlays (2 staged rounds).
    __shared__ __align__(16) u16 smem[2*KVT + 2*VVT];   // 33.8 KB
    __shared__ unsigned mb[64];                          // 2048-bit key mask

    const int id = blockIdx.x;                  // 512 blocks
    const int bh = (id&7)*4 + (id>>7);          // 4 heads per XCD
    const int qb = (id>>3)&15;
    const int b = bh>>4, h = bh&15;
    const int i0 = qb*128;
    const int tid = threadIdx.x;
    const int wv = tid>>6, lane = tid&63;
    const int l31 = lane&31, hi = lane>>5;
    const int hf = tid>>8;                      // kv half (== wv>>2)
    const int lt = tid&255;                     // staging thread within half
    const int wq = wv&3;                        // q-subtile within half

    u16* lk = smem + hf*KVT;                    // this half's K buf
    u16* lv = smem + 2*KVT + hf*VVT;            // this half's V buf

    const u16* Kp  = Kh + (size_t)bh*SEQ*HD + (size_t)hf*1024*HD;
    const u16* Vtp = Vt + (size_t)bh*HD*SEQ + hf*1024;   // col offset
    const int* mp  = mask + b*SEQ;

    // ---- prologue: mask bits, this half's tile 0 ----
    if (tid < 64){
        unsigned w = 0;
        #pragma unroll 8
        for (int i=0;i<32;i++) w |= (mp[tid*32+i] ? 1u:0u) << i;
        mb[tid] = w;
    }
    #pragma unroll
    for (int s=0;s<2;s++){
        int c = lt + s*256;                 // 512 chunks per tile
        int r = c>>3, c8 = c&7;
        *(uint4*)&lk[SW(r,c8)] = *(const uint4*)&Kp[(size_t)r*HD + c8*8];
        uint4 x = *(const uint4*)&Vtp[(size_t)r*SEQ + c8*8];
        uint2 xl; xl.x = x.x; xl.y = x.y;
        uint2 xh; xh.x = x.z; xh.y = x.w;
        *(uint2*)&lv[r*VROW + c8*8]     = xl;
        *(uint2*)&lv[r*VROW + c8*8 + 4] = xh;
    }

    // Q fragments direct from global (pre-scaled; B-frag: col=q, k=8*hi+j)
    const u16* Qrow = Qh + ((size_t)bh*SEQ + i0 + wq*32 + l31)*HD;
    bf16x8 aq[4];
    #pragma unroll
    for (int kk=0;kk<4;kk++) aq[kk] = *(const bf16x8*)&Qrow[kk*16 + hi*8];

    bf16x8 bones;
    #pragma unroll
    for (int j=0;j<8;j++) ((u16*)&bones)[j] = 0x3F80;

    f32x16 Oacc[2], Lacc;
    #pragma unroll
    for (int r=0;r<16;r++){ Oacc[0][r]=0.f; Oacc[1][r]=0.f; Lacc[r]=0.f; }

    __syncthreads();

    for (int t=0; t<16; t++){
        // prefetch next tile into VGPRs (latency hides under compute)
        uint4 gk[2], gv[2];
        if (t < 15){
            #pragma unroll
            for (int s=0;s<2;s++){
                int c = lt + s*256;
                int r = c>>3, c8 = c&7;
                gk[s] = *(const uint4*)&Kp[(size_t)(t*64+64+r)*HD + c8*8];
                gv[s] = *(const uint4*)&Vtp[(size_t)r*SEQ + t*64+64 + c8*8];
            }
        }

        __builtin_amdgcn_s_setprio(1);
        #pragma unroll
        for (int jt=0; jt<2; ++jt){
            // ---- S^T = K Q^T (swapped: col = q = lane&31) ----
            f32x16 sfr;
            #pragma unroll
            for (int r=0;r<16;r++) sfr[r]=0.f;
            #pragma unroll
            for (int kk=0;kk<4;kk++){
                bf16x8 ak = *(const bf16x8*)&lk[SW(jt*32+l31, 2*kk+hi)];
                sfr = __builtin_amdgcn_mfma_f32_32x32x16_bf16(ak, aq[kk], sfr, 0,0,0);
            }

            // ---- mask (skipped when word all-ones; uniform branch) ----
            unsigned mw = mb[(hf*16+t)*2 + jt];
            if ((unsigned)__builtin_amdgcn_readfirstlane((int)mw) != 0xFFFFFFFFu){
                unsigned ms = mw >> (hi*4);
                #pragma unroll
                for (int r=0;r<16;r++){
                    int kb = (r&3)+8*(r>>2);
                    if (!((ms>>kb)&1u)) sfr[r] = -1.0e9f;
                }
            }

            // ---- P = exp2(S) -> bf16 pairs, NATURAL order (no cross-lane) ----
            unsigned cc[8];
            #pragma unroll
            for (int d=0; d<8; ++d){
                float p0 = fast_exp2(sfr[2*d]);
                float p1 = fast_exp2(sfr[2*d+1]);
                cc[d] = (unsigned)f2bf(p0) | ((unsigned)f2bf(p1)<<16);
            }
            bf16x8 pa0, pa1;
            ((unsigned*)&pa0)[0]=cc[0]; ((unsigned*)&pa0)[1]=cc[1];
            ((unsigned*)&pa0)[2]=cc[2]; ((unsigned*)&pa0)[3]=cc[3];
            ((unsigned*)&pa1)[0]=cc[4]; ((unsigned*)&pa1)[1]=cc[5];
            ((unsigned*)&pa1)[2]=cc[6]; ((unsigned*)&pa1)[3]=cc[7];

            // ---- l += P*1 (order-invariant row sum; rows match Oacc) ----
            Lacc = __builtin_amdgcn_mfma_f32_32x32x16_bf16(pa0, bones, Lacc, 0,0,0);
            Lacc = __builtin_amdgcn_mfma_f32_32x32x16_bf16(pa1, bones, Lacc, 0,0,0);

            // ---- O += P V with V rows permuted to match natural P order ----
            #pragma unroll
            for (int dn=0; dn<2; ++dn){
                int vrb = (dn*32 + l31)*VROW + jt*32 + 4*hi;
                uint2 a0 = *(const uint2*)&lv[vrb];           // kp=0, lo
                uint2 a1 = *(const uint2*)&lv[vrb + 8];       // kp=0, hi
                uint2 b0 = *(const uint2*)&lv[vrb + 16];      // kp=1, lo
                uint2 b1 = *(const uint2*)&lv[vrb + 24];      // kp=1, hi
                union { uint4 u; bf16x8 v; } bv0, bv1;
                bv0.u.x=a0.x; bv0.u.y=a0.y; bv0.u.z=a1.x; bv0.u.w=a1.y;
                bv1.u.x=b0.x; bv1.u.y=b0.y; bv1.u.z=b1.x; bv1.u.w=b1.y;
                Oacc[dn] = __builtin_amdgcn_mfma_f32_32x32x16_bf16(pa0, bv0.v, Oacc[dn], 0,0,0);
                Oacc[dn] = __builtin_amdgcn_mfma_f32_32x32x16_bf16(pa1, bv1.v, Oacc[dn], 0,0,0);
            }
        }
        __builtin_amdgcn_s_setprio(0);

        if (t < 15){
            __syncthreads();   // (1) all waves done reading lk/lv this tile
            #pragma unroll
            for (int s=0;s<2;s++){
                int c = lt + s*256;
                int r = c>>3, c8 = c&7;
                *(uint4*)&lk[SW(r,c8)] = gk[s];
                uint2 xl; xl.x = gv[s].x; xl.y = gv[s].y;
                uint2 xh; xh.x = gv[s].z; xh.y = gv[s].w;
                *(uint2*)&lv[r*VROW + c8*8]     = xl;
                *(uint2*)&lv[r*VROW + c8*8 + 4] = xh;
            }
            __syncthreads();   // (2) commits visible for next tile
        }
    }

    // ---- merge kv-halves, staged (fits 33.8KB): round A = O[0]+l (stride 33
    // floats, 33792B exact); round B = O[1] (stride 17). ----
    __syncthreads();
    float* mrg = (float*)smem;
    const int slot = wq*64 + lane;
    float lm[16];
    if (hf == 1){
        float* p = mrg + (size_t)slot*33;
        #pragma unroll
        for (int r=0;r<16;r++) p[r]    = Oacc[0][r];
        #pragma unroll
        for (int r=0;r<16;r++) p[16+r] = Lacc[r];
    }
    __syncthreads();
    if (hf == 0){
        const float* p = mrg + (size_t)slot*33;
        #pragma unroll
        for (int r=0;r<16;r++) Oacc[0][r] += p[r];
        #pragma unroll
        for (int r=0;r<16;r++) lm[r] = Lacc[r] + p[16+r];
    }
    __syncthreads();
    if (hf == 1){
        float* p = mrg + (size_t)slot*17;
        #pragma unroll
        for (int r=0;r<16;r++) p[r] = Oacc[1][r];
    }
    __syncthreads();
    if (hf == 0){
        const float* p = mrg + (size_t)slot*17;
        #pragma unroll
        for (int r=0;r<16;r++) Oacc[1][r] += p[r];
        float rc[16];
        #pragma unroll
        for (int r=0;r<16;r++) rc[r] = 1.0f / lm[r];
        #pragma unroll
        for (int dn=0; dn<2; ++dn){
            int col = h*HD + dn*32 + l31;
            #pragma unroll
            for (int r=0;r<16;r++){
                int row = i0 + wq*32 + (r&3) + 8*(r>>2) + 4*hi;
                ctx[((size_t)(b*SEQ+row))*D_MODEL + col] = f2bf(Oacc[dn][r] * rc[r]);
            }
        }
    }
}

// ---------------------------------------------------------------------------
extern "C" void kernel_launch(void* const* d_in, const int* in_sizes, int n_in,
                              void* d_out, int out_size, void* d_ws, size_t ws_size,
                              hipStream_t stream)
{
    (void)in_sizes; (void)n_in; (void)out_size; (void)ws_size;
    const u16* q    = (const u16*)d_in[0];
    const u16* k    = (const u16*)d_in[1];
    const u16* v    = (const u16*)d_in[2];
    const int* mask = (const int*)d_in[3];
    const u16* Wq   = (const u16*)d_in[4];
    const u16* Wk   = (const u16*)d_in[5];
    const u16* Wv   = (const u16*)d_in[6];
    const u16* Wo   = (const u16*)d_in[7];

    const size_t TEN = (size_t)MROWS * D_MODEL;   // 4 Mi elements
    const size_t WEL = (size_t)D_MODEL * D_MODEL; // 1 Mi
    u16* qb  = (u16*)d_ws;        // converted bf16 (convert_all order)
    u16* kb  = qb + TEN;
    u16* vb  = kb + TEN;
    u16* Wqb = vb + TEN;
    u16* Wkb = Wqb + WEL;
    u16* Wvb = Wkb + WEL;
    u16* Wob = Wvb + WEL;
    u16* Qh  = Wob + WEL;         // [B,H,L,HD] (pre-scaled by 0.125*log2e)
    u16* Kh  = Qh + TEN;
    u16* Vtr = Kh + TEN;          // [B,H,HD,L]
    u16* ctx = Vtr + TEN;         // [B,L,D]

    dim3 bb(256);
    convert_all<<<dim3(16384), bb, 0, stream>>>(q,k,v,Wq,Wk,Wv,Wo, qb);
    gemm_qkv<<<dim3(8,32,3), dim3(512), 0, stream>>>(qb,kb,vb, Wqb,Wkb,Wvb, Qh,Kh,Vtr);
    attn3<<<dim3(512), dim3(512), 0, stream>>>(Qh, Kh, Vtr, mask, ctx);
    gemm_out<<<dim3(8,64), dim3(512), 0, stream>>>(ctx, Wob, d_out, q);
}

// Round 14
// 215.134 us; speedup vs baseline: 2.4431x; 2.4431x over previous
//
#include <hip/hip_runtime.h>

// B=2, L=2048, D=1024, H=16, Hd=64, no causal mask. Inputs f32 (device-sniffed).

#define D_MODEL 1024
#define NH 16
#define HD 64
#define BATCH 2
#define SEQ 2048
#define MROWS (BATCH*SEQ)   // 4096

typedef unsigned short u16;
typedef __bf16 bf16x8 __attribute__((ext_vector_type(8)));
typedef float f32x4 __attribute__((ext_vector_type(4)));
typedef float f32x16 __attribute__((ext_vector_type(16)));

__device__ __forceinline__ u16 f2bf(float f){
    __bf16 h = (__bf16)f;                    // hw v_cvt (RNE) on gfx950
    return __builtin_bit_cast(u16, h);
}
__device__ __forceinline__ float fast_exp2(float x){ return __builtin_amdgcn_exp2f(x); }

// async global->LDS, 16B per lane (m97 pattern). LDS dest must be
// wave-uniform base + lane*16 in issue order.
__device__ __forceinline__ void stage16(const void* g, void* l){
#if __has_builtin(__builtin_amdgcn_global_load_lds)
    __builtin_amdgcn_global_load_lds(
        (__attribute__((address_space(1))) void*)(unsigned long long)(g),
        (__attribute__((address_space(3))) void*)(unsigned int)(unsigned long long)(l),
        16, 0, 0);
#else
    *(uint4*)l = *(const uint4*)g;
#endif
}

// f32-vs-bf16 sniff on a pristine input buffer (deterministic, graph-safe).
__device__ __forceinline__ int detect_f32_block(const u16* q, int tid){
    __shared__ int flag;
    if (tid < 64){
        unsigned e = (q[2*tid]>>7)&0xFFu;
        bool hit = (e>=115u)&&(e<=132u);
        unsigned long long m = __ballot(hit);
        if (tid==0) flag = (__popcll(m) < 32) ? 1 : 0;
    }
    __syncthreads();
    return flag;
}

// ---------------------------------------------------------------------------
// One launch converts q,k,v,Wq,Wk,Wv,Wo into contiguous bf16 ws regions.
// Grid-strided: 2048 blocks x 8 iters (G11 memory-bound grid sizing).
// ---------------------------------------------------------------------------
__global__ __launch_bounds__(256)
void convert_all(const u16* __restrict__ q, const u16* __restrict__ k,
                 const u16* __restrict__ v, const u16* __restrict__ Wq,
                 const u16* __restrict__ Wk, const u16* __restrict__ Wv,
                 const u16* __restrict__ Wo, u16* __restrict__ dst)
{
    int isf32 = detect_f32_block(q, threadIdx.x);
    for (int bid = blockIdx.x; bid < 16384; bid += 2048){
        const u16* src; int lb;
        if      (bid < 4096)  { src=q;  lb=bid; }
        else if (bid < 8192)  { src=k;  lb=bid-4096; }
        else if (bid < 12288) { src=v;  lb=bid-8192; }
        else if (bid < 13312) { src=Wq; lb=bid-12288; }
        else if (bid < 14336) { src=Wk; lb=bid-13312; }
        else if (bid < 15360) { src=Wv; lb=bid-14336; }
        else                  { src=Wo; lb=bid-15360; }
        size_t so = (size_t)lb*1024 + threadIdx.x*4;
        size_t dofs = (size_t)bid*1024 + threadIdx.x*4;
        if (isf32){
            float4 x = *(const float4*)((const float*)src + so);
            ushort4 o; o.x=f2bf(x.x); o.y=f2bf(x.y); o.z=f2bf(x.z); o.w=f2bf(x.w);
            *(ushort4*)(dst+dofs) = o;
        } else {
            *(ushort4*)(dst+dofs) = *(const ushort4*)(src+so);
        }
    }
}

// ---------------------------------------------------------------------------
// Fused Q/K/V projection GEMM, BK=64, symmetric double-buffer, 512 threads /
// 8 waves (R11-verified). Wave tile 32x64 (acc 2x4), staging 2 chunks/thread
// per operand. 64KB LDS, 2 blocks/CU -> 16 waves/CU. XOR-8 pre-swizzled
// source chunks + same XOR at frag read (0 conflicts). XCD-bijective swizzle.
// z<2 -> split-head [B,H,L,HD]; z==2 -> transposed [B,H,HD,L] for PV.
// z==0 folds the softmax scale 1/sqrt(64)*log2(e) into Q.
// ---------------------------------------------------------------------------
__global__ __launch_bounds__(512)
void gemm_qkv(const u16* __restrict__ qb, const u16* __restrict__ kb,
              const u16* __restrict__ vb, const u16* __restrict__ Wqb,
              const u16* __restrict__ Wkb, const u16* __restrict__ Wvb,
              u16* __restrict__ Qh, u16* __restrict__ Kh, u16* __restrict__ Vt)
{
    const int K = 1024;
    __shared__ __align__(16) u16 lA[2][128*64];   // 32KB
    __shared__ __align__(16) u16 lB[2][128*64];   // 32KB

    // bijective XCD remap of (x,y,z): 768 = 8 xcd * (8 x * 12 panels)
    const int lid = blockIdx.x + 8*(blockIdx.y + 32*blockIdx.z);
    const int xcd = lid & 7, loc = lid >> 3;
    const int xb = loc & 7, p = loc >> 3;
    const int yz = xcd*12 + p;
    const int z = yz >> 5, yb = yz & 31;

    const u16* A  = (z==0)? qb  : (z==1)? kb  : vb;
    const u16* Bt = (z==0)? Wqb : (z==1)? Wkb : Wvb;

    const int tid  = threadIdx.x;
    const int wid  = tid>>6, lane = tid&63;
    const int quad = lane>>4, l16 = lane&15;
    const int wm = (wid&3)*32, wn = (wid>>2)*64;   // 8 waves: 4 row x 2 col
    const int row0 = yb*128, col0 = xb*128;

    f32x4 acc[2][4];
    #pragma unroll
    for (int i=0;i<2;i++)
        #pragma unroll
        for (int j=0;j<4;j++) acc[i][j] = (f32x4){0.f,0.f,0.f,0.f};

    // 1024 chunks per operand; 512 threads -> 2 chunks/thread (XOR source)
    #define QKV_STAGE(buf, k0)                                                 \
        _Pragma("unroll")                                                      \
        for (int s=0;s<2;s++){                                                 \
            int c = tid + s*512;                                               \
            int row = c>>3, cr = c&7;                                          \
            int gc = cr ^ (row&7);                                             \
            stage16(&A [(size_t)(row0+row)*K + (k0) + gc*8], &lA[buf][c*8]);   \
            stage16(&Bt[(size_t)(col0+row)*K + (k0) + gc*8], &lB[buf][c*8]);   \
        }

    QKV_STAGE(0, 0)
    __syncthreads();

    int cur = 0;
    for (int t=0; t<16; ++t){
        if (t < 15) QKV_STAGE(cur^1, (t+1)*64)     // async over this tile's compute
        #pragma unroll
        for (int kk=0;kk<2;kk++){
            bf16x8 af[2], bfr[4];
            #pragma unroll
            for (int mi=0;mi<2;mi++){
                int r = wm + mi*16 + l16;
                af[mi] = *(const bf16x8*)&lA[cur][r*64 + ((kk*4+quad) ^ (r&7))*8];
            }
            #pragma unroll
            for (int ni=0;ni<4;ni++){
                int r = wn + ni*16 + l16;
                bfr[ni] = *(const bf16x8*)&lB[cur][r*64 + ((kk*4+quad) ^ (r&7))*8];
            }
            #pragma unroll
            for (int mi=0;mi<2;mi++)
                #pragma unroll
                for (int ni=0;ni<4;ni++)
                    acc[mi][ni] = __builtin_amdgcn_mfma_f32_16x16x32_bf16(af[mi], bfr[ni], acc[mi][ni], 0,0,0);
        }
        __syncthreads();   // single drain: vmcnt(0)+barrier, next buf ready
        cur ^= 1;
    }
    #undef QKV_STAGE

    const float qsc = (z==0) ? 0.18033688011112042f : 1.0f; // 0.125*log2(e)
    u16* Csh = (z==0)? Qh : Kh;
    #pragma unroll
    for (int mi=0;mi<2;mi++){
        #pragma unroll
        for (int ni=0;ni<4;ni++){
            int col = col0 + wn + ni*16 + l16;
            #pragma unroll
            for (int r=0;r<4;r++){
                int row = row0 + wm + mi*16 + quad*4 + r;
                u16 o = f2bf(acc[mi][ni][r]*qsc);
                int b = row>>11, i = row&2047, h = col>>6, d = col&63;
                if (z<2) Csh[((((size_t)(b*NH+h))*SEQ + i)<<6) + d] = o;
                else     Vt[((size_t)((b*NH+h)*HD + d))*SEQ + i] = o;
            }
        }
    }
}

// ---------------------------------------------------------------------------
// Output projection: C = ctx * Wo^T. 64x128 tiles, BK=64, symmetric dbuf,
// 512 threads / 8 waves (R12-verified): wave tile 32x32 (acc 2x2), staging
// A 1 + B 2 chunks per thread. LDS 48KB -> 2 blocks/CU -> 16 waves/CU.
// XOR-8 source+read swizzle. XCD swizzle.
// ---------------------------------------------------------------------------
__global__ __launch_bounds__(512)
void gemm_out(const u16* __restrict__ A, const u16* __restrict__ Bt,
              void* __restrict__ Cv, const u16* __restrict__ qref)
{
    const int K = 1024, N = 1024;
    int outf32 = detect_f32_block(qref, threadIdx.x);
    __shared__ __align__(16) u16 lA[2][64*64];    // 16KB
    __shared__ __align__(16) u16 lB[2][128*64];   // 32KB
    const int tid  = threadIdx.x;
    const int wid  = tid>>6, lane = tid&63;
    const int quad = lane>>4, l16 = lane&15;
    const int wm = (wid&1)*32, wn = (wid>>1)*32;   // 8 waves: 2 row x 4 col

    // bijective XCD remap: 512 = 8 xcd * (8 x * 8 y)
    const int lid = blockIdx.x + 8*blockIdx.y;
    const int xcd = lid & 7, loc = lid >> 3;
    const int xb = loc & 7, yb = xcd*8 + (loc>>3);
    const int row0 = yb*64, col0 = xb*128;

    f32x4 acc[2][2];
    #pragma unroll
    for (int i=0;i<2;i++)
        #pragma unroll
        for (int j=0;j<2;j++) acc[i][j] = (f32x4){0.f,0.f,0.f,0.f};

    // A: 512 chunks -> 1/thread; B: 1024 chunks -> 2/thread (XOR source)
    #define OUT_STAGE(buf, k0)                                                 \
        {                                                                      \
            int c2 = tid;                                                      \
            int row = c2>>3, cr = c2&7;                                        \
            int gc = cr ^ (row&7);                                             \
            stage16(&A[(size_t)(row0+row)*K + (k0) + gc*8], &lA[buf][c2*8]);   \
        }                                                                      \
        _Pragma("unroll")                                                      \
        for (int s=0;s<2;s++){                                                 \
            int c = tid + s*512;                                               \
            int row = c>>3, cr = c&7;                                          \
            int gc = cr ^ (row&7);                                             \
            stage16(&Bt[(size_t)(col0+row)*K + (k0) + gc*8], &lB[buf][c*8]);   \
        }

    OUT_STAGE(0, 0)
    __syncthreads();

    int cur = 0;
    for (int t=0; t<16; ++t){
        if (t < 15) OUT_STAGE(cur^1, (t+1)*64)
        #pragma unroll
        for (int kk=0;kk<2;kk++){
            bf16x8 af[2], bfr[2];
            #pragma unroll
            for (int mi=0;mi<2;mi++){
                int r = wm + mi*16 + l16;
                af[mi] = *(const bf16x8*)&lA[cur][r*64 + ((kk*4+quad) ^ (r&7))*8];
            }
            #pragma unroll
            for (int ni=0;ni<2;ni++){
                int r = wn + ni*16 + l16;
                bfr[ni] = *(const bf16x8*)&lB[cur][r*64 + ((kk*4+quad) ^ (r&7))*8];
            }
            #pragma unroll
            for (int mi=0;mi<2;mi++)
                #pragma unroll
                for (int ni=0;ni<2;ni++)
                    acc[mi][ni] = __builtin_amdgcn_mfma_f32_16x16x32_bf16(af[mi], bfr[ni], acc[mi][ni], 0,0,0);
        }
        __syncthreads();
        cur ^= 1;
    }
    #undef OUT_STAGE

    #pragma unroll
    for (int mi=0;mi<2;mi++){
        #pragma unroll
        for (int ni=0;ni<2;ni++){
            int col = col0 + wn + ni*16 + l16;
            #pragma unroll
            for (int r=0;r<4;r++){
                int row = row0 + wm + mi*16 + quad*4 + r;
                float f = acc[mi][ni][r];
                if (outf32) ((float*)Cv)[(size_t)row*N + col] = f;
                else        ((u16*)Cv)[(size_t)row*N + col] = f2bf(f);
            }
        }
    }
}

// ---------------------------------------------------------------------------
// Flash attention v6 (R12-verified, 55.5us): 32x32x16 swapped QK^T,
// natural-order in-register P, V-row-permuted PV, ones-MFMA l, KV-split
// (8 waves, halves merge via LDS), V pitch 68, K/V LDS double-buffered.
// NOTE: register-file cap (≈128 combined VGPR+AGPR state) limits this
// kernel to 16 waves/CU; do NOT force higher min-occupancy bounds (R13:
// launch_bounds(512,8) -> 64-reg cap -> full spill, 6.5x slower).
// ---------------------------------------------------------------------------
#define KVT 4096                      // K buffer: 64 rows * 64 elems
#define VROW 68                       // V row pitch (pad 4)
#define VVT (64*VROW)                 // 4352 elems per V buffer
// elem offset of 16B chunk c8 (0..7) in swizzled K row (stride 64):
#define SW(row, c8) ((row)*64 + ((((c8) ^ ((row)&7)))*8))

__global__ __launch_bounds__(512, 4)
void attn3(const u16* __restrict__ Qh, const u16* __restrict__ Kh,
           const u16* __restrict__ Vt, const int* __restrict__ mask,
           u16* __restrict__ ctx)
{
    // carve: K bufs [hf][dbuf] then V bufs [hf][dbuf]; merge overlays all.
    __shared__ __align__(16) u16 smem[4*KVT + 4*VVT];   // 67.6 KB
    __shared__ unsigned mb[64];                          // 2048-bit key mask

    const int id = blockIdx.x;                  // 512 blocks
    const int bh = (id&7)*4 + (id>>7);          // 4 heads per XCD
    const int qb = (id>>3)&15;
    const int b = bh>>4, h = bh&15;
    const int i0 = qb*128;
    const int tid = threadIdx.x;
    const int wv = tid>>6, lane = tid&63;
    const int l31 = lane&31, hi = lane>>5;
    const int hf = tid>>8;                      // kv half (== wv>>2)
    const int lt = tid&255;                     // staging thread within half
    const int wq = wv&3;                        // q-subtile within half

    u16* lkh = smem + (hf*2)*KVT;               // this half's two K bufs
    u16* lvh = smem + 4*KVT + (hf*2)*VVT;       // this half's two V bufs

    const u16* Kp  = Kh + (size_t)bh*SEQ*HD + (size_t)hf*1024*HD;
    const u16* Vtp = Vt + (size_t)bh*HD*SEQ + hf*1024;   // col offset
    const int* mp  = mask + b*SEQ;

    // ---- prologue: mask bits, this half's tile 0 -> buf 0 ----
    if (tid < 64){
        unsigned w = 0;
        #pragma unroll 8
        for (int i=0;i<32;i++) w |= (mp[tid*32+i] ? 1u:0u) << i;
        mb[tid] = w;
    }
    #pragma unroll
    for (int s=0;s<2;s++){
        int c = lt + s*256;                 // 512 chunks per tile
        int r = c>>3, c8 = c&7;
        *(uint4*)&lkh[SW(r,c8)] = *(const uint4*)&Kp[(size_t)r*HD + c8*8];
        uint4 x = *(const uint4*)&Vtp[(size_t)r*SEQ + c8*8];
        uint2 xl; xl.x = x.x; xl.y = x.y;
        uint2 xh; xh.x = x.z; xh.y = x.w;
        *(uint2*)&lvh[r*VROW + c8*8]     = xl;
        *(uint2*)&lvh[r*VROW + c8*8 + 4] = xh;
    }

    // Q fragments direct from global (pre-scaled; B-frag: col=q, k=8*hi+j)
    const u16* Qrow = Qh + ((size_t)bh*SEQ + i0 + wq*32 + l31)*HD;
    bf16x8 aq[4];
    #pragma unroll
    for (int kk=0;kk<4;kk++) aq[kk] = *(const bf16x8*)&Qrow[kk*16 + hi*8];

    bf16x8 bones;
    #pragma unroll
    for (int j=0;j<8;j++) ((u16*)&bones)[j] = 0x3F80;

    f32x16 Oacc[2], Lacc;
    #pragma unroll
    for (int r=0;r<16;r++){ Oacc[0][r]=0.f; Oacc[1][r]=0.f; Lacc[r]=0.f; }

    for (int t=0; t<16; t++){
        u16* lkc = lkh + (t&1)*KVT;
        u16* lvc = lvh + (t&1)*VVT;
        u16* lkn = lkh + ((t&1)^1)*KVT;
        u16* lvn = lvh + ((t&1)^1)*VVT;

        __syncthreads();

        // prefetch next tile into VGPRs (HBM/L2 latency hides under compute)
        uint4 gk[2], gv[2];
        if (t < 15){
            #pragma unroll
            for (int s=0;s<2;s++){
                int c = lt + s*256;
                int r = c>>3, c8 = c&7;
                gk[s] = *(const uint4*)&Kp[(size_t)(t*64+64+r)*HD + c8*8];
                gv[s] = *(const uint4*)&Vtp[(size_t)r*SEQ + t*64+64 + c8*8];
            }
        }

        __builtin_amdgcn_s_setprio(1);
        #pragma unroll
        for (int jt=0; jt<2; ++jt){
            // ---- S^T = K Q^T (swapped: col = q = lane&31) ----
            f32x16 sfr;
            #pragma unroll
            for (int r=0;r<16;r++) sfr[r]=0.f;
            #pragma unroll
            for (int kk=0;kk<4;kk++){
                bf16x8 ak = *(const bf16x8*)&lkc[SW(jt*32+l31, 2*kk+hi)];
                sfr = __builtin_amdgcn_mfma_f32_32x32x16_bf16(ak, aq[kk], sfr, 0,0,0);
            }

            // ---- mask (skipped when word all-ones; uniform branch) ----
            unsigned mw = mb[(hf*16+t)*2 + jt];
            if ((unsigned)__builtin_amdgcn_readfirstlane((int)mw) != 0xFFFFFFFFu){
                unsigned ms = mw >> (hi*4);
                #pragma unroll
                for (int r=0;r<16;r++){
                    int kb = (r&3)+8*(r>>2);
                    if (!((ms>>kb)&1u)) sfr[r] = -1.0e9f;
                }
            }

            // ---- P = exp2(S) -> bf16 pairs, NATURAL order (no cross-lane) ----
            unsigned cc[8];
            #pragma unroll
            for (int d=0; d<8; ++d){
                float p0 = fast_exp2(sfr[2*d]);
                float p1 = fast_exp2(sfr[2*d+1]);
                cc[d] = (unsigned)f2bf(p0) | ((unsigned)f2bf(p1)<<16);
            }
            bf16x8 pa0, pa1;
            ((unsigned*)&pa0)[0]=cc[0]; ((unsigned*)&pa0)[1]=cc[1];
            ((unsigned*)&pa0)[2]=cc[2]; ((unsigned*)&pa0)[3]=cc[3];
            ((unsigned*)&pa1)[0]=cc[4]; ((unsigned*)&pa1)[1]=cc[5];
            ((unsigned*)&pa1)[2]=cc[6]; ((unsigned*)&pa1)[3]=cc[7];

            // ---- l += P*1 (order-invariant row sum; rows match Oacc) ----
            Lacc = __builtin_amdgcn_mfma_f32_32x32x16_bf16(pa0, bones, Lacc, 0,0,0);
            Lacc = __builtin_amdgcn_mfma_f32_32x32x16_bf16(pa1, bones, Lacc, 0,0,0);

            // ---- O += P V with V rows permuted to match natural P order ----
            #pragma unroll
            for (int dn=0; dn<2; ++dn){
                int vrb = (dn*32 + l31)*VROW + jt*32 + 4*hi;
                uint2 a0 = *(const uint2*)&lvc[vrb];          // kp=0, lo
                uint2 a1 = *(const uint2*)&lvc[vrb + 8];      // kp=0, hi
                uint2 b0 = *(const uint2*)&lvc[vrb + 16];     // kp=1, lo
                uint2 b1 = *(const uint2*)&lvc[vrb + 24];     // kp=1, hi
                union { uint4 u; bf16x8 v; } bv0, bv1;
                bv0.u.x=a0.x; bv0.u.y=a0.y; bv0.u.z=a1.x; bv0.u.w=a1.y;
                bv1.u.x=b0.x; bv1.u.y=b0.y; bv1.u.z=b1.x; bv1.u.w=b1.y;
                Oacc[dn] = __builtin_amdgcn_mfma_f32_32x32x16_bf16(pa0, bv0.v, Oacc[dn], 0,0,0);
                Oacc[dn] = __builtin_amdgcn_mfma_f32_32x32x16_bf16(pa1, bv1.v, Oacc[dn], 0,0,0);
            }
        }
        __builtin_amdgcn_s_setprio(0);

        // ---- commit prefetched tile ----
        if (t < 15){
            #pragma unroll
            for (int s=0;s<2;s++){
                int c = lt + s*256;
                int r = c>>3, c8 = c&7;
                *(uint4*)&lkn[SW(r,c8)] = gk[s];
                uint2 xl; xl.x = gv[s].x; xl.y = gv[s].y;
                uint2 xh; xh.x = gv[s].z; xh.y = gv[s].w;
                *(uint2*)&lvn[r*VROW + c8*8]     = xl;
                *(uint2*)&lvn[r*VROW + c8*8 + 4] = xh;
            }
        }
    }

    // ---- merge kv-halves: half B dumps (O,l) to LDS, half A adds ----
    __syncthreads();
    float* mrg = (float*)smem;                  // overlays K/V bufs (done)
    if (hf == 1){
        float* p = mrg + (size_t)(wq*64 + lane)*49;
        #pragma unroll
        for (int dn=0; dn<2; ++dn)
            #pragma unroll
            for (int r=0;r<16;r++) p[dn*16+r] = Oacc[dn][r];
        #pragma unroll
        for (int r=0;r<16;r++) p[32+r] = Lacc[r];
    }
    __syncthreads();
    if (hf == 0){
        const float* p = mrg + (size_t)(wq*64 + lane)*49;
        #pragma unroll
        for (int dn=0; dn<2; ++dn)
            #pragma unroll
            for (int r=0;r<16;r++) Oacc[dn][r] += p[dn*16+r];
        float rc[16];
        #pragma unroll
        for (int r=0;r<16;r++) rc[r] = 1.0f / (Lacc[r] + p[32+r]);
        #pragma unroll
        for (int dn=0; dn<2; ++dn){
            int col = h*HD + dn*32 + l31;
            #pragma unroll
            for (int r=0;r<16;r++){
                int row = i0 + wq*32 + (r&3) + 8*(r>>2) + 4*hi;
                ctx[((size_t)(b*SEQ+row))*D_MODEL + col] = f2bf(Oacc[dn][r] * rc[r]);
            }
        }
    }
}

// ---------------------------------------------------------------------------
extern "C" void kernel_launch(void* const* d_in, const int* in_sizes, int n_in,
                              void* d_out, int out_size, void* d_ws, size_t ws_size,
                              hipStream_t stream)
{
    (void)in_sizes; (void)n_in; (void)out_size; (void)ws_size;
    const u16* q    = (const u16*)d_in[0];
    const u16* k    = (const u16*)d_in[1];
    const u16* v    = (const u16*)d_in[2];
    const int* mask = (const int*)d_in[3];
    const u16* Wq   = (const u16*)d_in[4];
    const u16* Wk   = (const u16*)d_in[5];
    const u16* Wv   = (const u16*)d_in[6];
    const u16* Wo   = (const u16*)d_in[7];

    const size_t TEN = (size_t)MROWS * D_MODEL;   // 4 Mi elements
    const size_t WEL = (size_t)D_MODEL * D_MODEL; // 1 Mi
    u16* qb  = (u16*)d_ws;        // converted bf16 (convert_all order)
    u16* kb  = qb + TEN;
    u16* vb  = kb + TEN;
    u16* Wqb = vb + TEN;
    u16* Wkb = Wqb + WEL;
    u16* Wvb = Wkb + WEL;
    u16* Wob = Wvb + WEL;
    u16* Qh  = Wob + WEL;         // [B,H,L,HD] (pre-scaled by 0.125*log2e)
    u16* Kh  = Qh + TEN;
    u16* Vtr = Kh + TEN;          // [B,H,HD,L]
    u16* ctx = Vtr + TEN;         // [B,L,D]

    dim3 bb(256);
    convert_all<<<dim3(2048), bb, 0, stream>>>(q,k,v,Wq,Wk,Wv,Wo, qb);
    gemm_qkv<<<dim3(8,32,3), dim3(512), 0, stream>>>(qb,kb,vb, Wqb,Wkb,Wvb, Qh,Kh,Vtr);
    attn3<<<dim3(512), dim3(512), 0, stream>>>(Qh, Kh, Vtr, mask, ctx);
    gemm_out<<<dim3(8,64), dim3(512), 0, stream>>>(ctx, Wob, d_out, q);
}